// Round 6
// baseline (207.798 us; speedup 1.0000x reference)
//
#include <hip/hip_runtime.h>

#define CHANNELS 3
#define HW 512
#define KS 15
#define GPAD 7
#define TX 64
#define TY 48
#define HTY (TY + 2 * GPAD)    // 62 staged rows
#define NCOL (TX + 2 * GPAD)   // 78 staged cols [gx0-7, gx0+71)
#define IN_STR 81              // odd stride: all read/write phases <=2-way (free)
#define GRIDY ((HW + TY - 1) / TY)  // 11
#define HWIN (16 + KS - 1)     // 30-tap window, 16 outputs (horizontal)
#define VOUT 12                // rows per thread (vertical): 4 groups x 12 = 48
#define VWIN (VOUT + KS - 1)   // 26-tap window (vertical)

__global__ __launch_bounds__(256, 8)  // LDS 20088B -> 8 blocks/CU; VGPR <= 64
void gauss_blur_kernel(const float* __restrict__ x,
                       const float* __restrict__ sigma,
                       float* __restrict__ out) {
    // Single LDS buffer reused in place:
    //   phase 0: input rows [gy0, gy0+62) x cols [gx0-7, gx0+71)  (62 x 78)
    //   phase 2: horizontal result (mid) overwrites cols [0, 64)
    __shared__ float in_s[HTY * IN_STR];  // 62 x 81 x 4 = 20088 B

    const int tid   = threadIdx.x;
    const int tileX = blockIdx.x;   // 0..7
    const int tileY = blockIdx.y;   // 0..10
    const int bc    = blockIdx.z;   // 0..95
    const int b     = bc / CHANNELS;

    // per-batch 1D Gaussian weights (separable; S^2+1e-8 vs (S1)^2 diff <=1e-8 rel)
    float w[KS];
    {
        const float s = sigma[b];
        const float inv_denom = 1.0f / (2.0f * s * s + 1e-8f);
        float sum = 0.0f;
        #pragma unroll
        for (int i = 0; i < KS; ++i) {
            const float d = (float)(i - GPAD);
            const float g = __expf(-d * d * inv_denom);
            w[i] = g;
            sum += g;
        }
        const float inv = 1.0f / sum;
        #pragma unroll
        for (int i = 0; i < KS; ++i) w[i] *= inv;
    }

    const size_t plane = (size_t)HW * HW;
    const float* xp = x + (size_t)bc * plane;
    float* op       = out + (size_t)bc * plane;
    const int gx0 = tileX * TX;
    const int gy0 = tileY * TY - GPAD;
    const int ax0 = gx0 - GPAD;

    // ---- phase 0: stage input -> LDS. Scalar coalesced loads, consecutive-lane
    // -> consecutive LDS address writes (conflict-free; <=3-way only at the 78->81
    // row wrap). Interior blocks take a check-free fast path (wave-uniform). ----
    const bool interior = (tileX > 0) & (tileX < HW / TX - 1) &
                          (tileY > 0) & (gy0 + HTY <= HW);
    if (interior) {
        const float* src0 = xp + (size_t)gy0 * HW + ax0;
        for (int i = tid; i < HTY * NCOL; i += 256) {
            const int r = i / NCOL;
            const int c = i - r * NCOL;
            in_s[r * IN_STR + c] = src0[(size_t)r * HW + c];
        }
    } else {
        for (int i = tid; i < HTY * NCOL; i += 256) {
            const int r = i / NCOL;
            const int c = i - r * NCOL;
            const int gy = gy0 + r;
            const int gc = ax0 + c;
            float v = 0.0f;
            if ((unsigned)gy < (unsigned)HW && (unsigned)gc < (unsigned)HW)
                v = xp[(size_t)gy * HW + gc];
            in_s[r * IN_STR + c] = v;
        }
    }
    __syncthreads();

    // ---- phase 1: horizontal pass, LDS -> registers. 248 items (<=1/thread):
    // item -> (row tid>>2, chunk tid&3). Output local col oc = 16*ch + o reads
    // staged cols [oc, oc+30). Tap bound: output o receives window index
    // j in [o, o+14] -> per-j range o in [max(j-14,0), min(j,15)]. ----
    float acc[16];
    #pragma unroll
    for (int o = 0; o < 16; ++o) acc[o] = 0.0f;
    const int hr  = tid >> 2;
    const int hch = tid & 3;
    if (tid < HTY * 4) {
        const float* src = &in_s[hr * IN_STR + 16 * hch];
        #pragma unroll
        for (int j = 0; j < HWIN; ++j) {
            const float v = src[j];
            const int lo = (j - (KS - 1)) > 0 ? (j - (KS - 1)) : 0;
            const int hi = (j < 16) ? j : 15;   // min(j, 15) — NOT KS-1 (r5 bug)
            #pragma unroll
            for (int o = lo; o <= hi; ++o)
                acc[o] = fmaf(w[j - o], v, acc[o]);
        }
    }
    __syncthreads();   // all phase-1 reads complete before in-place overwrite

    // ---- phase 2: write mid back into the same buffer, cols [0,64) ----
    if (tid < HTY * 4) {
        float* dst = &in_s[hr * IN_STR + 16 * hch];
        #pragma unroll
        for (int o = 0; o < 16; ++o) dst[o] = acc[o];
    }
    __syncthreads();

    // ---- phase 3: vertical pass from LDS; coalesced 256B/wave stores.
    // Thread -> (col tid&63, 12 rows). ----
    {
        const int c  = tid & (TX - 1);
        const int r0 = (tid >> 6) * VOUT;
        float vacc[VOUT];
        #pragma unroll
        for (int o = 0; o < VOUT; ++o) vacc[o] = 0.0f;
        #pragma unroll
        for (int j = 0; j < VWIN; ++j) {
            const float v = in_s[(r0 + j) * IN_STR + c];
            const int lo = (j - (KS - 1)) > 0 ? (j - (KS - 1)) : 0;
            const int hi = (j < VOUT) ? j : (VOUT - 1);  // min(j, VOUT-1)
            #pragma unroll
            for (int o = lo; o <= hi; ++o)
                vacc[o] = fmaf(w[j - o], v, vacc[o]);
        }
        const int gx   = gx0 + c;
        const int row0 = tileY * TY + r0;
        if (tileY * TY + TY <= HW) {   // wave-uniform: full tile
            #pragma unroll
            for (int o = 0; o < VOUT; ++o)
                op[(size_t)(row0 + o) * HW + gx] = vacc[o];
        } else {                        // last y-tile: clip rows 512..527
            #pragma unroll
            for (int o = 0; o < VOUT; ++o)
                if (row0 + o < HW)
                    op[(size_t)(row0 + o) * HW + gx] = vacc[o];
        }
    }
}

extern "C" void kernel_launch(void* const* d_in, const int* in_sizes, int n_in,
                              void* d_out, int out_size, void* d_ws, size_t ws_size,
                              hipStream_t stream) {
    const float* x     = (const float*)d_in[0];
    const float* sigma = (const float*)d_in[1];
    float* out         = (float*)d_out;
    const int B = in_sizes[1];  // 32
    dim3 grid(HW / TX, GRIDY, B * CHANNELS);
    gauss_blur_kernel<<<grid, dim3(256, 1, 1), 0, stream>>>(x, sigma, out);
}